// Round 5
// baseline (99.696 us; speedup 1.0000x reference)
//
#include <hip/hip_runtime.h>

typedef __attribute__((ext_vector_type(8))) short short8;
typedef __attribute__((ext_vector_type(4))) float f32x4;
typedef unsigned int u32;

#define ROW_B 1056          // 66 w-chunks * 16 B (8 bf16 channels per chunk); 64 written, 2 pad
#define SLOT_B 6336         // 6 h-rows per d-plane slot
#define NSLOT 4

__device__ __forceinline__ unsigned short f2bf(float f) {
  unsigned u = __builtin_bit_cast(unsigned, f);
  u += 0x7FFFu + ((u >> 16) & 1u);          // RNE (inputs finite)
  return (unsigned short)(u >> 16);
}
__device__ __forceinline__ u32 cvtpk(float lo, float hi) {
  u32 r;
  asm("v_cvt_pk_bf16_f32 %0, %1, %2" : "=v"(r) : "v"(lo), "v"(hi));
  return r;
}

#define MF(ACC, H, FR, KD, KH)                                                \
  ACC[H][wt] = __builtin_amdgcn_mfma_f32_16x16x32_bf16(FR, bfragB[KD][KH],    \
                                                       ACC[H][wt], 0, 0, 0)
#define MFI(ACC, H, FR)                                                       \
  ACC[H][wt] = __builtin_amdgcn_mfma_f32_16x16x32_bf16(FR, bfragB[0][0],      \
                                                       zf4, 0, 0, 0)

// iter dp: stage plane dp+2 (sync: load 8ch -> cvt -> one ds_write_b128; the
// vmcnt stall is hidden by OTHER waves' MFMAs at 12 waves/CU), compute plane
// dp from slot dp&3, barrier only after odd dp (4-slot ring gives 2-iter
// write->read distance), close gen dp-2 (all-register maxpool).
// AN = gen(dp) opened with C=0 MFMA; AM = gen(dp-1) kd=1; AO = gen(dp-2) kd=2.
#define PROC(DP, AN, AM, AO, K1, K2, DOCLOSE, SAVEP, DOSTAGE, DOBAR)          \
  {                                                                           \
    const int dp_ = (DP);                                                     \
    if (DOSTAGE) stage(dp_ + 2);                                              \
    const int sb_ = (dp_ & 3) * SLOT_B + rowbase;                             \
    __builtin_amdgcn_s_setprio(1);                                            \
    _Pragma("unroll") for (int wt = 0; wt < 2; ++wt) {                        \
      const short8 f0 = *(const short8*)(smem + sb_ + 0 * ROW_B + physoff[wt]); \
      const short8 f1 = *(const short8*)(smem + sb_ + 1 * ROW_B + physoff[wt]); \
      const short8 f2 = *(const short8*)(smem + sb_ + 2 * ROW_B + physoff[wt]); \
      const short8 f3 = *(const short8*)(smem + sb_ + 3 * ROW_B + physoff[wt]); \
      MFI(AN, 0, f0); MFI(AN, 1, f1);                                         \
      MF(AN, 0, f1, 0, 1); MF(AN, 1, f2, 0, 1);                               \
      MF(AN, 0, f2, 0, 2); MF(AN, 1, f3, 0, 2);                               \
      if (K1) {                                                               \
        MF(AM, 0, f0, 1, 0); MF(AM, 1, f1, 1, 0);                             \
        MF(AM, 0, f1, 1, 1); MF(AM, 1, f2, 1, 1);                             \
        MF(AM, 0, f2, 1, 2); MF(AM, 1, f3, 1, 2);                             \
      }                                                                       \
      if (K2) {                                                               \
        MF(AO, 0, f0, 2, 0); MF(AO, 1, f1, 2, 0);                             \
        MF(AO, 0, f1, 2, 1); MF(AO, 1, f2, 2, 1);                             \
        MF(AO, 0, f2, 2, 2); MF(AO, 1, f3, 2, 2);                             \
      }                                                                       \
    }                                                                         \
    __builtin_amdgcn_s_setprio(0);                                            \
    if (DOBAR) __syncthreads();                                               \
    if (DOCLOSE) {                                                            \
      _Pragma("unroll") for (int wt = 0; wt < 2; ++wt) {                      \
        const float e01 = fmaxf(fmaxf(AO[0][wt][0], AO[0][wt][1]),            \
                                fmaxf(AO[1][wt][0], AO[1][wt][1]));           \
        const float e23 = fmaxf(fmaxf(AO[0][wt][2], AO[0][wt][3]),            \
                                fmaxf(AO[1][wt][2], AO[1][wt][3]));           \
        if (SAVEP) {                                                          \
          p01[wt] = e01; p23[wt] = e23;                                       \
        } else if (pairvalid) {                                               \
          sum += fmaxf(p01[wt], e01);                                         \
          if (!(wt == 1 && wmask)) sum += fmaxf(p23[wt], e23);                \
        }                                                                     \
      }                                                                       \
    }                                                                         \
  }

// grid: 1024 = 64 b * 16 h-quartets ; block: 256 = 4 waves {h-pair}x{w-half}
__launch_bounds__(256, 3)
__global__ void conv_fused(const float* __restrict__ x,
                           const float* __restrict__ cw,
                           float* __restrict__ ws) {
  __shared__ __align__(16) unsigned char smem[NSLOT * SLOT_B];  // 25344 B
  __shared__ float wsum[4];

  // XCD-chunked swizzle (1024 % 8 == 0, bijective): adjacent-hq blocks
  // (sharing 2 input rows) land on the same XCD's L2.
  const int rb  = blockIdx.x;
  const int bid = (rb & 7) * 128 + (rb >> 3);
  const int b   = bid >> 4;
  const int hq  = bid & 15;

  const int tid  = threadIdx.x;
  const int lane = tid & 63;
  const int wid  = tid >> 6;
  const int nm   = lane & 15;
  const int g    = lane >> 4;
  const int hp   = wid >> 1;      // h'-pair within quartet
  const int wh   = wid & 1;       // w-half

  const float* xb = x + (size_t)b * (8u * 32u * 64u * 64u);

  // ---- B fragments: 9 (kd,kh) weight-sets, K = kw*8 + c (24 used, 8 pad) ----
  short8 bfragB[3][3];
#pragma unroll
  for (int kd = 0; kd < 3; ++kd)
#pragma unroll
    for (int kh = 0; kh < 3; ++kh) {
      short8 f;
#pragma unroll
      for (int j = 0; j < 8; ++j) {
        float v = (g < 3) ? cw[(nm * 8 + j) * 27 + kd * 9 + kh * 3 + g] : 0.f;
        f[j] = (short)f2bf(v);
      }
      bfragB[kd][kh] = f;
    }

  // ---- A-fragment chunk offsets (reads bank-conflict-free by pigeonhole) ----
  const int gc = (g < 3) ? g : 2;     // pad lanes read real data, weight = 0
  int physoff[2];
#pragma unroll
  for (int wt = 0; wt < 2; ++wt)
    physoff[wt] = ((2 * wh + wt) * 16 + nm + gc) * 16;
  const int rowbase = (2 * hp) * ROW_B;

  // ---- staging: 384 slots = 6 rows x 64 w; pass0 all threads, pass1 tid<128 ----
  const int w0    = tid & 63;
  const int srow0 = tid >> 6;               // rows 0..3
  const int srow1 = 4 + (srow0 & 1);        // rows 4..5 (tid<128)
  int h0 = 4 * hq + srow0; if (h0 > 63) h0 = 63;
  int h1 = 4 * hq + srow1; if (h1 > 63) h1 = 63;
  const float* st_base0 = xb + h0 * 64 + w0;
  const float* st_base1 = xb + h1 * 64 + w0;
  const int st_off0 = srow0 * ROW_B + w0 * 16;
  const int st_off1 = srow1 * ROW_B + w0 * 16;
  const bool act1 = (tid < 128);

  auto stage = [&](int p) {
    unsigned char* d = smem + (p & 3) * SLOT_B;
    {
      const float* sp = st_base0 + p * 4096;
      float v[8];
#pragma unroll
      for (int c = 0; c < 8; ++c) v[c] = sp[(size_t)c * 131072];
      uint4 q;
      q.x = cvtpk(v[0], v[1]); q.y = cvtpk(v[2], v[3]);
      q.z = cvtpk(v[4], v[5]); q.w = cvtpk(v[6], v[7]);
      *(uint4*)(d + st_off0) = q;
    }
    if (act1) {
      const float* sp = st_base1 + p * 4096;
      float v[8];
#pragma unroll
      for (int c = 0; c < 8; ++c) v[c] = sp[(size_t)c * 131072];
      uint4 q;
      q.x = cvtpk(v[0], v[1]); q.y = cvtpk(v[2], v[3]);
      q.z = cvtpk(v[4], v[5]); q.w = cvtpk(v[6], v[7]);
      *(uint4*)(d + st_off1) = q;
    }
  };

  // validity: pooled h-pair (4hq+2hp, +1) needs both h' <= 61
  const bool pairvalid = !(hq == 15 && hp == 1);
  // w' 62,63 = global chunk 3 (wh==1, wt==1), g==3, regs 2,3
  const bool wmask = (wh == 1) && (g == 3);

  const f32x4 zf4 = {0.f, 0.f, 0.f, 0.f};
  float sum = 0.f;
  float p01[2], p23[2];
  f32x4 accA[2][2], accB[2][2], accC[2][2];    // gen % 3 rotation

  stage(0);
  stage(1);
  __syncthreads();

  // prologue: gens 0,1 open
  PROC(0, accA, accB, accC, 0, 0, 0, 0, 1, 0)
  PROC(1, accB, accA, accC, 1, 0, 0, 0, 1, 1)

  // main: dp = 2..25, closures d' = 0..23 (even=save, odd=combine)
  for (int p0 = 2; p0 <= 20; p0 += 6) {
    PROC(p0 + 0, accC, accB, accA, 1, 1, 1, 1, 1, 0)
    PROC(p0 + 1, accA, accC, accB, 1, 1, 1, 0, 1, 1)
    PROC(p0 + 2, accB, accA, accC, 1, 1, 1, 1, 1, 0)
    PROC(p0 + 3, accC, accB, accA, 1, 1, 1, 0, 1, 1)
    PROC(p0 + 4, accA, accC, accB, 1, 1, 1, 1, 1, 0)
    PROC(p0 + 5, accB, accA, accC, 1, 1, 1, 0, 1, 1)
  }
  // epilogue: dp = 26..31 (staging stops after plane 31)
  PROC(26, accC, accB, accA, 1, 1, 1, 1, 1, 0)
  PROC(27, accA, accC, accB, 1, 1, 1, 0, 1, 1)
  PROC(28, accB, accA, accC, 1, 1, 1, 1, 1, 0)
  PROC(29, accC, accB, accA, 1, 1, 1, 0, 1, 1)
  PROC(30, accA, accC, accB, 1, 1, 1, 1, 0, 0)
  PROC(31, accB, accA, accC, 1, 1, 1, 0, 0, 0)

  // block reduce -> one partial per block (stored by LOGICAL bid)
#pragma unroll
  for (int off = 32; off > 0; off >>= 1) sum += __shfl_down(sum, off);
  __syncthreads();                 // reuse guard before wsum
  if (lane == 0) wsum[wid] = sum;
  __syncthreads();
  if (tid == 0) ws[bid] = wsum[0] + wsum[1] + wsum[2] + wsum[3];
}

// out[b] = 0.5 * S_b / 14415 + 0.5 * sum(conv_bias) + sum(bias)
__global__ void finalize_k(const float* __restrict__ ws,
                           const float* __restrict__ cb,
                           const float* __restrict__ bias,
                           float* __restrict__ out) {
  const int b = threadIdx.x;
  float s = 0.f;
#pragma unroll
  for (int hq = 0; hq < 16; ++hq) s += ws[b * 16 + hq];
  float cbs = 0.f, bs = 0.f;
#pragma unroll
  for (int c = 0; c < 16; ++c) { cbs += cb[c]; bs += bias[c]; }
  out[b] = 0.5f * s / 14415.f + 0.5f * cbs + bs;
}

extern "C" void kernel_launch(void* const* d_in, const int* in_sizes, int n_in,
                              void* d_out, int out_size, void* d_ws, size_t ws_size,
                              hipStream_t stream) {
  const float* x    = (const float*)d_in[0];
  const float* cw   = (const float*)d_in[1];
  const float* cb   = (const float*)d_in[2];
  const float* bias = (const float*)d_in[3];
  float* out = (float*)d_out;
  float* ws  = (float*)d_ws;   // 1024 floats

  hipLaunchKernelGGL(conv_fused, dim3(1024), dim3(256), 0, stream, x, cw, ws);
  hipLaunchKernelGGL(finalize_k, dim3(1), dim3(64), 0, stream, ws, cb, bias, out);
}

// Round 6
// 75.387 us; speedup vs baseline: 1.3225x; 1.3225x over previous
//
#include <hip/hip_runtime.h>

typedef __attribute__((ext_vector_type(8))) short short8;
typedef __attribute__((ext_vector_type(4))) float f32x4;
typedef unsigned int u32;

#define ROW_B 1056          // 66 w-chunks * 16 B (8 bf16 channels per chunk); 64 written, 2 pad
#define SLOT_B 10560        // 10 h-rows per d-plane
#define NSLOT 4

__device__ __forceinline__ unsigned short f2bf(float f) {
  unsigned u = __builtin_bit_cast(unsigned, f);
  u += 0x7FFFu + ((u >> 16) & 1u);          // RNE (inputs finite)
  return (unsigned short)(u >> 16);
}
__device__ __forceinline__ u32 cvtpk(float lo, float hi) {
  u32 r;
  asm("v_cvt_pk_bf16_f32 %0, %1, %2" : "=v"(r) : "v"(lo), "v"(hi));
  return r;
}

#define MF(ACC, H, FR, KD, KH)                                                \
  ACC[H][wt] = __builtin_amdgcn_mfma_f32_16x16x32_bf16(FR, bfragB[KD][KH],    \
                                                       ACC[H][wt], 0, 0, 0)
#define MFI(ACC, H, FR)                                                       \
  ACC[H][wt] = __builtin_amdgcn_mfma_f32_16x16x32_bf16(FR, bfragB[0][0],      \
                                                       zf4, 0, 0, 0)

// Interval [even dp, dp+1], one barrier per interval (4-slot ring: reads touch
// slots dp&3,(dp+1)&3; writes (dp+2)&3,(dp+3)&3 - disjoint, so the mid barrier
// is removable). Per PROC: issue loads(dp+2) (latency hidden under this
// plane's MFMA burst), compute plane dp, cvt+write(dp+2), close gen dp-2.
// AN = gen(dp) opened via C=0 MFMA (skipped when K0=0: gens 30,31 don't
// exist); AM = gen(dp-1) kd=1; AO = gen(dp-2) kd=2.
#define PROC(DP, AN, AM, AO, K0, K1, K2, DOCLOSE, SAVEP, DOSTAGE, DOBAR)      \
  {                                                                           \
    const int dp_ = (DP);                                                     \
    if (DOSTAGE) {                                                            \
      stage_load(dp_ + 2);                                                    \
      __builtin_amdgcn_sched_barrier(0);  /* pin loads before MFMA phase */   \
    }                                                                         \
    const int sb_ = (dp_ & 3) * SLOT_B + rowbase;                             \
    __builtin_amdgcn_s_setprio(1);                                            \
    _Pragma("unroll") for (int wt = 0; wt < 4; ++wt) {                        \
      const short8 f0 = *(const short8*)(smem + sb_ + 0 * ROW_B + physoff[wt]); \
      const short8 f1 = *(const short8*)(smem + sb_ + 1 * ROW_B + physoff[wt]); \
      const short8 f2 = *(const short8*)(smem + sb_ + 2 * ROW_B + physoff[wt]); \
      const short8 f3 = *(const short8*)(smem + sb_ + 3 * ROW_B + physoff[wt]); \
      if (K0) {                                                               \
        MFI(AN, 0, f0); MFI(AN, 1, f1);                                       \
        MF(AN, 0, f1, 0, 1); MF(AN, 1, f2, 0, 1);                             \
        MF(AN, 0, f2, 0, 2); MF(AN, 1, f3, 0, 2);                             \
      }                                                                       \
      if (K1) {                                                               \
        MF(AM, 0, f0, 1, 0); MF(AM, 1, f1, 1, 0);                             \
        MF(AM, 0, f1, 1, 1); MF(AM, 1, f2, 1, 1);                             \
        MF(AM, 0, f2, 1, 2); MF(AM, 1, f3, 1, 2);                             \
      }                                                                       \
      if (K2) {                                                               \
        MF(AO, 0, f0, 2, 0); MF(AO, 1, f1, 2, 0);                             \
        MF(AO, 0, f1, 2, 1); MF(AO, 1, f2, 2, 1);                             \
        MF(AO, 0, f2, 2, 2); MF(AO, 1, f3, 2, 2);                             \
      }                                                                       \
    }                                                                         \
    __builtin_amdgcn_s_setprio(0);                                            \
    if (DOSTAGE) stage_write(dp_ + 2);                                        \
    if (DOBAR) __syncthreads();                                               \
    if (DOCLOSE) {                                                            \
      _Pragma("unroll") for (int wt = 0; wt < 4; ++wt) {                      \
        const float e01 = fmaxf(fmaxf(AO[0][wt][0], AO[0][wt][1]),            \
                                fmaxf(AO[1][wt][0], AO[1][wt][1]));           \
        const float e23 = fmaxf(fmaxf(AO[0][wt][2], AO[0][wt][3]),            \
                                fmaxf(AO[1][wt][2], AO[1][wt][3]));           \
        if (SAVEP) {                                                          \
          p01[wt] = e01; p23[wt] = e23;                                       \
        } else if (hvalid) {                                                  \
          sum += fmaxf(p01[wt], e01);                                         \
          if (!(wt == 3 && g == 3)) sum += fmaxf(p23[wt], e23);               \
        }                                                                     \
      }                                                                       \
    }                                                                         \
  }

// grid: 512 = 64 b * 8 h-octets ; block: 256 (4 waves x 2 h'-rows each)
__launch_bounds__(256, 2)
__global__ void conv_fused(const float* __restrict__ x,
                           const float* __restrict__ cw,
                           float* __restrict__ ws) {
  __shared__ __align__(16) unsigned char smem[NSLOT * SLOT_B];
  __shared__ float wsum[4];

  // XCD-chunked bijective swizzle (512 % 8 == 0): 64 consecutive logical
  // blocks (8 images x their 8 h-octets) per XCD -> same-image input rows
  // hit the same XCD L2.
  const int rb  = blockIdx.x;
  const int bid = (rb & 7) * 64 + (rb >> 3);
  const int b   = bid >> 3;
  const int hq  = bid & 7;
  const int h0  = hq * 8;

  const int tid  = threadIdx.x;
  const int lane = tid & 63;
  const int wid  = tid >> 6;
  const int nm   = lane & 15;
  const int g    = lane >> 4;

  const float* xb = x + (size_t)b * (8u * 32u * 64u * 64u);

  // ---- B fragments: 9 (kd,kh) weight-sets, K = kw*8 + c (24 used, 8 pad) ----
  short8 bfragB[3][3];
#pragma unroll
  for (int kd = 0; kd < 3; ++kd)
#pragma unroll
    for (int kh = 0; kh < 3; ++kh) {
      short8 f;
#pragma unroll
      for (int j = 0; j < 8; ++j) {
        float v = (g < 3) ? cw[(nm * 8 + j) * 27 + kd * 9 + kh * 3 + g] : 0.f;
        f[j] = (short)f2bf(v);
      }
      bfragB[kd][kh] = f;
    }

  // ---- A-fragment chunk offsets (reads are bank-conflict-free by pigeonhole) ----
  const int gc = (g < 3) ? g : 2;     // pad lanes read real data, weight = 0
  int physoff[4];
#pragma unroll
  for (int wt = 0; wt < 4; ++wt) physoff[wt] = (wt * 16 + nm + gc) * 16;
  const int rowbase = (2 * wid) * ROW_B;

  // ---- staging: slot s = row*64 + w ; thread gathers 8 channels, one b128 write ----
  bool st_act[3]; const float* st_base[3]; int st_off[3];
#pragma unroll
  for (int pass = 0; pass < 3; ++pass) {
    const int t = tid + pass * 256;
    bool act = (t < 640);
    int row = (t >> 6) % 10;
    const int w = t & 63;
    int h = h0 + row;
    if (h > 63) { act = false; h = 63; }
    st_act[pass]  = act;
    st_base[pass] = xb + h * 64 + w;           // channel 0, plane 0
    st_off[pass]  = row * ROW_B + w * 16;
  }

  float ld[3][8];   // single in-flight staging buffer (24 VGPRs)

  auto stage_load = [&](int p) {
#pragma unroll
    for (int pass = 0; pass < 3; ++pass) {
      if (st_act[pass]) {
        const float* sp = st_base[pass] + p * 4096;
#pragma unroll
        for (int c = 0; c < 8; ++c) ld[pass][c] = sp[(size_t)c * 131072];
      }
    }
  };
  auto stage_write = [&](int p) {
    unsigned char* d = smem + (p & 3) * SLOT_B;
#pragma unroll
    for (int pass = 0; pass < 3; ++pass) {
      if (st_act[pass]) {
        uint4 v;
        v.x = cvtpk(ld[pass][0], ld[pass][1]);
        v.y = cvtpk(ld[pass][2], ld[pass][3]);
        v.z = cvtpk(ld[pass][4], ld[pass][5]);
        v.w = cvtpk(ld[pass][6], ld[pass][7]);
        *(uint4*)(d + st_off[pass]) = v;
      }
    }
  };

  const bool hvalid = !(hq == 7 && wid == 3);  // h' 62,63 invalid
  const f32x4 zf4 = {0.f, 0.f, 0.f, 0.f};
  float sum = 0.f;
  float p01[4], p23[4];
  f32x4 accA[2][4], accB[2][4], accC[2][4];    // gen % 3 rotation

  // prologue: planes 0,1 staged synchronously
  stage_load(0); stage_write(0);
  stage_load(1); stage_write(1);
  __syncthreads();

  //            AN    AM    AO    K0 K1 K2 CL SV ST BAR
  PROC(0, accA, accB, accC, 1, 0, 0, 0, 0, 1, 0)
  PROC(1, accB, accA, accC, 1, 1, 0, 0, 0, 1, 1)

  // main: dp = 2..25, closures d' = 0..23 (even=save, odd=combine)
  for (int p0 = 2; p0 <= 20; p0 += 6) {
    PROC(p0 + 0, accC, accB, accA, 1, 1, 1, 1, 1, 1, 0)
    PROC(p0 + 1, accA, accC, accB, 1, 1, 1, 1, 0, 1, 1)
    PROC(p0 + 2, accB, accA, accC, 1, 1, 1, 1, 1, 1, 0)
    PROC(p0 + 3, accC, accB, accA, 1, 1, 1, 1, 0, 1, 1)
    PROC(p0 + 4, accA, accC, accB, 1, 1, 1, 1, 1, 1, 0)
    PROC(p0 + 5, accB, accA, accC, 1, 1, 1, 1, 0, 1, 1)
  }
  // epilogue: dp = 26..31 (staging stops after plane 31; gens 30,31 skipped)
  PROC(26, accC, accB, accA, 1, 1, 1, 1, 1, 1, 0)
  PROC(27, accA, accC, accB, 1, 1, 1, 1, 0, 1, 1)
  PROC(28, accB, accA, accC, 1, 1, 1, 1, 1, 1, 0)
  PROC(29, accC, accB, accA, 1, 1, 1, 1, 0, 1, 1)
  PROC(30, accA, accC, accB, 0, 1, 1, 1, 1, 0, 0)
  PROC(31, accB, accA, accC, 0, 0, 1, 1, 0, 0, 0)

  // block reduce -> one partial per block (stored by LOGICAL bid)
#pragma unroll
  for (int off = 32; off > 0; off >>= 1) sum += __shfl_down(sum, off);
  if (lane == 0) wsum[wid] = sum;
  __syncthreads();
  if (tid == 0) ws[bid] = wsum[0] + wsum[1] + wsum[2] + wsum[3];
}

// out[b] = 0.5 * S_b / 14415 + 0.5 * sum(conv_bias) + sum(bias)
__global__ void finalize_k(const float* __restrict__ ws,
                           const float* __restrict__ cb,
                           const float* __restrict__ bias,
                           float* __restrict__ out) {
  const int b = threadIdx.x;
  float s = 0.f;
#pragma unroll
  for (int hq = 0; hq < 8; ++hq) s += ws[b * 8 + hq];
  float cbs = 0.f, bs = 0.f;
#pragma unroll
  for (int c = 0; c < 16; ++c) { cbs += cb[c]; bs += bias[c]; }
  out[b] = 0.5f * s / 14415.f + 0.5f * cbs + bs;
}

extern "C" void kernel_launch(void* const* d_in, const int* in_sizes, int n_in,
                              void* d_out, int out_size, void* d_ws, size_t ws_size,
                              hipStream_t stream) {
  const float* x    = (const float*)d_in[0];
  const float* cw   = (const float*)d_in[1];
  const float* cb   = (const float*)d_in[2];
  const float* bias = (const float*)d_in[3];
  float* out = (float*)d_out;
  float* ws  = (float*)d_ws;   // 512 floats

  hipLaunchKernelGGL(conv_fused, dim3(512), dim3(256), 0, stream, x, cw, ws);
  hipLaunchKernelGGL(finalize_k, dim3(1), dim3(64), 0, stream, ws, cb, bias, out);
}